// Round 1
// baseline (1439.002 us; speedup 1.0000x reference)
//
#include <hip/hip_runtime.h>
#include <math.h>

#define LN_EPS 1e-5f

// ---------------- tiled fp32 GEMM:  C[N,M] = A[N,K] @ W[K,M] + bias[M] ----------------
__global__ __launch_bounds__(256)
void gemm_bias(const float* __restrict__ A, const float* __restrict__ W,
               const float* __restrict__ bias, float* __restrict__ C,
               int Nr, int K, int M) {
  __shared__ float As[32][68];   // As[k][m], +4 pad keeps float4 alignment & banks spread
  __shared__ float Ws[32][68];   // Ws[k][n]
  const int bm = blockIdx.x * 64;
  const int bn = blockIdx.y * 64;
  const int tid = threadIdx.x;
  const int tx = tid & 15, ty = tid >> 4;
  float acc[4][4] = {};
  for (int k0 = 0; k0 < K; k0 += 32) {
#pragma unroll
    for (int i = 0; i < 8; ++i) {          // A tile: 64x32, coalesced along K
      int lin = tid + i * 256;
      int m = lin >> 5, kk = lin & 31;
      int row = bm + m;
      As[kk][m] = (row < Nr) ? A[(size_t)row * K + k0 + kk] : 0.f;
    }
#pragma unroll
    for (int i = 0; i < 8; ++i) {          // W tile: 32x64, coalesced along M
      int lin = tid + i * 256;
      int kk = lin >> 6, n = lin & 63;
      Ws[kk][n] = W[(size_t)(k0 + kk) * M + bn + n];
    }
    __syncthreads();
#pragma unroll
    for (int kk = 0; kk < 32; ++kk) {
      float4 a = *(const float4*)&As[kk][ty * 4];
      float4 w = *(const float4*)&Ws[kk][tx * 4];
      float av[4] = {a.x, a.y, a.z, a.w};
      float wv[4] = {w.x, w.y, w.z, w.w};
#pragma unroll
      for (int i = 0; i < 4; ++i)
#pragma unroll
        for (int j = 0; j < 4; ++j) acc[i][j] += av[i] * wv[j];
    }
    __syncthreads();
  }
#pragma unroll
  for (int i = 0; i < 4; ++i) {
    int row = bm + ty * 4 + i;
    if (row < Nr) {
#pragma unroll
      for (int j = 0; j < 4; ++j) {
        int col = bn + tx * 4 + j;
        C[(size_t)row * M + col] = acc[i][j] + bias[col];
      }
    }
  }
}

// ---------------- edge pass A: scores -> exp -> den (atomic) ----------------
// 128 threads per edge: t = h*16+d. Softmax max-subtraction skipped (shift-invariant,
// scores ~N(0,2), no overflow risk in f32).
__global__ __launch_bounds__(256)
void edge_pass_a(const int* __restrict__ ei, const float* __restrict__ ea,
                 const float* __restrict__ eW, const float* __restrict__ eb,
                 const float* __restrict__ q, const float* __restrict__ k,
                 float* __restrict__ exb, float* __restrict__ den, int E) {
  __shared__ float eas[2][32];
  const int tid = threadIdx.x;
  const int el = tid >> 7, t = tid & 127;
  const long e = (long)blockIdx.x * 2 + el;
  const bool valid = e < E;
  int s = 0, dd = 0;
  if (valid) { s = ei[e]; dd = ei[E + e]; }
  if (valid && t < 32) eas[el][t] = ea[e * 32 + t];   // coalesced edge_attr row
  __syncthreads();
  if (!valid) return;
  const int h = t >> 4, d = t & 15;
  float p = q[(size_t)s * 128 + t] * k[(size_t)dd * 128 + t];
  p += __shfl_xor(p, 8);
  p += __shfl_xor(p, 4);
  p += __shfl_xor(p, 2);
  p += __shfl_xor(p, 1);
  if (d == 0) {
    float bsum = eb[h];
#pragma unroll
    for (int i = 0; i < 32; ++i) bsum += eas[el][i] * eW[i * 8 + h];
    float sc = p * 0.25f + bsum;          // /sqrt(16)
    float ex = expf(sc);
    exb[e * 8 + h] = ex;
    atomicAdd(&den[(size_t)dd * 8 + h], ex);
  }
}

// ---------------- edge pass B: scatter v[src]*attn into agg[dst] ----------------
__global__ __launch_bounds__(256)
void edge_pass_b(const int* __restrict__ ei, const float* __restrict__ v,
                 const float* __restrict__ exb, const float* __restrict__ den,
                 float* __restrict__ agg, int E) {
  const int tid = threadIdx.x;
  const int el = tid >> 7, t = tid & 127;
  const long e = (long)blockIdx.x * 2 + el;
  if (e >= E) return;
  const int s = ei[e], dd = ei[E + e];
  const int h = t >> 4;
  const float attn = exb[e * 8 + h] / fmaxf(den[(size_t)dd * 8 + h], 1e-8f);
  atomicAdd(&agg[(size_t)dd * 128 + t], v[(size_t)s * 128 + t] * attn);
}

// ---------------- y = LN(x + r) * g + b, rows of 128 (1 wave/row) ----------------
__global__ __launch_bounds__(256)
void add_ln128(const float* __restrict__ x, const float* __restrict__ r,
               const float* __restrict__ g, const float* __restrict__ b,
               float* __restrict__ y, int Nr) {
  const int wid = threadIdx.x >> 6, lane = threadIdx.x & 63;
  const long row = (long)blockIdx.x * 4 + wid;
  if (row >= Nr) return;
  const float2 xv = *(const float2*)&x[row * 128 + lane * 2];
  const float2 rv = *(const float2*)&r[row * 128 + lane * 2];
  float a0 = xv.x + rv.x, a1 = xv.y + rv.y;
  float s = a0 + a1, ss = a0 * a0 + a1 * a1;
#pragma unroll
  for (int off = 32; off; off >>= 1) { s += __shfl_xor(s, off); ss += __shfl_xor(ss, off); }
  const float mu = s * (1.f / 128.f);
  const float inv = rsqrtf(ss * (1.f / 128.f) - mu * mu + LN_EPS);
  const float2 gv = *(const float2*)&g[lane * 2];
  const float2 bv = *(const float2*)&b[lane * 2];
  float2 o;
  o.x = (a0 - mu) * inv * gv.x + bv.x;
  o.y = (a1 - mu) * inv * gv.y + bv.y;
  *(float2*)&y[row * 128 + lane * 2] = o;
}

// ---------------- in-place LN(row of 512) -> exact GELU ----------------
__global__ __launch_bounds__(256)
void ln_gelu512(float* __restrict__ hbuf, const float* __restrict__ g,
                const float* __restrict__ b, int Nr) {
  __shared__ float rs[4], rss[4];
  const long row = blockIdx.x;
  const int tid = threadIdx.x;
  float2 v = *(float2*)&hbuf[row * 512 + tid * 2];
  float s = v.x + v.y, ss = v.x * v.x + v.y * v.y;
#pragma unroll
  for (int off = 32; off; off >>= 1) { s += __shfl_xor(s, off); ss += __shfl_xor(ss, off); }
  const int wid = tid >> 6, lane = tid & 63;
  if (lane == 0) { rs[wid] = s; rss[wid] = ss; }
  __syncthreads();
  s = rs[0] + rs[1] + rs[2] + rs[3];
  ss = rss[0] + rss[1] + rss[2] + rss[3];
  const float mu = s * (1.f / 512.f);
  const float inv = rsqrtf(ss * (1.f / 512.f) - mu * mu + LN_EPS);
  float t0 = (v.x - mu) * inv * g[tid * 2] + b[tid * 2];
  float t1 = (v.y - mu) * inv * g[tid * 2 + 1] + b[tid * 2 + 1];
  v.x = 0.5f * t0 * (1.f + erff(t0 * 0.70710678118654752f));
  v.y = 0.5f * t1 * (1.f + erff(t1 * 0.70710678118654752f));
  *(float2*)&hbuf[row * 512 + tid * 2] = v;
}

extern "C" void kernel_launch(void* const* d_in, const int* in_sizes, int n_in,
                              void* d_out, int out_size, void* d_ws, size_t ws_size,
                              hipStream_t stream) {
  const float* x   = (const float*)d_in[0];
  const int*   ei  = (const int*)d_in[1];
  const float* ea  = (const float*)d_in[2];
  const float* qW  = (const float*)d_in[3];
  const float* qbi = (const float*)d_in[4];
  const float* kW  = (const float*)d_in[5];
  const float* kbi = (const float*)d_in[6];
  const float* vW  = (const float*)d_in[7];
  const float* vbi = (const float*)d_in[8];
  const float* eW  = (const float*)d_in[9];
  const float* eb  = (const float*)d_in[10];
  const float* oW  = (const float*)d_in[11];
  const float* ob  = (const float*)d_in[12];
  const float* ln1_g = (const float*)d_in[13];
  const float* ln1_b = (const float*)d_in[14];
  const float* f1W = (const float*)d_in[15];
  const float* f1b = (const float*)d_in[16];
  const float* lnf_g = (const float*)d_in[17];
  const float* lnf_b = (const float*)d_in[18];
  const float* f2W = (const float*)d_in[19];
  const float* f2b = (const float*)d_in[20];
  const float* ln2_g = (const float*)d_in[21];
  const float* ln2_b = (const float*)d_in[22];
  float* out = (float*)d_out;

  const int N = in_sizes[0] / 128;
  const int E = in_sizes[1] / 2;
  const size_t NH  = (size_t)N * 128;   // 6.4M floats
  const size_t NHh = (size_t)N * 8;     // 0.4M floats

  // workspace layout (floats), with deliberate lifetime-based overlap:
  //   q:0  k:NH  v:2NH  ex:3NH  den:4NH  agg:4NH+NHh (ends 5NH+NHh)
  //   attnout = ex slot; x1 = q slot; h = [NH, 5NH) (dead k/v/ex/den + agg head);
  //   h2 = 5NH+NHh. Total = 6NH + NHh floats (~155 MB).
  float* base = (float*)d_ws;
  float* wq   = base;
  float* wk   = base + NH;
  float* wv   = base + 2 * NH;
  float* exb  = base + 3 * NH;
  float* den  = base + 4 * NH;
  float* agg  = base + 4 * NH + NHh;
  float* attnout = exb;            // free after edge pass B
  float* x1   = wq;                // q free after edge pass A
  float* hbuf = wk;                // N*512 floats over dead k/v/ex/den/agg-head
  float* h2   = base + 5 * NH + NHh;

  dim3 blk(256);
  dim3 g128((N + 63) / 64, 2);
  dim3 g512((N + 63) / 64, 8);
  const int egrid = (E + 1) / 2;

  // QKV projections
  gemm_bias<<<g128, blk, 0, stream>>>(x, qW, qbi, wq, N, 128, 128);
  gemm_bias<<<g128, blk, 0, stream>>>(x, kW, kbi, wk, N, 128, 128);
  gemm_bias<<<g128, blk, 0, stream>>>(x, vW, vbi, wv, N, 128, 128);

  // edge scores + softmax denominator
  hipMemsetAsync(den, 0, NHh * sizeof(float), stream);
  edge_pass_a<<<egrid, blk, 0, stream>>>(ei, ea, eW, eb, wq, wk, exb, den, E);

  // weighted aggregation
  hipMemsetAsync(agg, 0, NH * sizeof(float), stream);
  edge_pass_b<<<egrid, blk, 0, stream>>>(ei, wv, exb, den, agg, E);

  // output projection + residual LN
  gemm_bias<<<g128, blk, 0, stream>>>(agg, oW, ob, attnout, N, 128, 128);
  add_ln128<<<dim3((N + 3) / 4), blk, 0, stream>>>(x, attnout, ln1_g, ln1_b, x1, N);

  // FFN
  gemm_bias<<<g512, blk, 0, stream>>>(x1, f1W, f1b, hbuf, N, 128, 512);
  ln_gelu512<<<dim3(N), blk, 0, stream>>>(hbuf, lnf_g, lnf_b, N);
  gemm_bias<<<g128, blk, 0, stream>>>(hbuf, f2W, f2b, h2, N, 512, 128);
  add_ln128<<<dim3((N + 3) / 4), blk, 0, stream>>>(x1, h2, ln2_g, ln2_b, out, N);
}

// Round 2
// 838.726 us; speedup vs baseline: 1.7157x; 1.7157x over previous
//
#include <hip/hip_runtime.h>
#include <math.h>

#define LN_EPS 1e-5f

// ---------------- tiled fp32 GEMM:  C[N,M] = A[N,K] @ W[K,M] + bias[M] ----------------
__global__ __launch_bounds__(256)
void gemm_bias(const float* __restrict__ A, const float* __restrict__ W,
               const float* __restrict__ bias, float* __restrict__ C,
               int Nr, int K, int M) {
  __shared__ float As[32][68];
  __shared__ float Ws[32][68];
  const int bm = blockIdx.x * 64;
  const int bn = blockIdx.y * 64;
  const int tid = threadIdx.x;
  const int tx = tid & 15, ty = tid >> 4;
  float acc[4][4] = {};
  for (int k0 = 0; k0 < K; k0 += 32) {
#pragma unroll
    for (int i = 0; i < 8; ++i) {
      int lin = tid + i * 256;
      int m = lin >> 5, kk = lin & 31;
      int row = bm + m;
      As[kk][m] = (row < Nr) ? A[(size_t)row * K + k0 + kk] : 0.f;
    }
#pragma unroll
    for (int i = 0; i < 8; ++i) {
      int lin = tid + i * 256;
      int kk = lin >> 6, n = lin & 63;
      Ws[kk][n] = W[(size_t)(k0 + kk) * M + bn + n];
    }
    __syncthreads();
#pragma unroll
    for (int kk = 0; kk < 32; ++kk) {
      float4 a = *(const float4*)&As[kk][ty * 4];
      float4 w = *(const float4*)&Ws[kk][tx * 4];
      float av[4] = {a.x, a.y, a.z, a.w};
      float wv[4] = {w.x, w.y, w.z, w.w};
#pragma unroll
      for (int i = 0; i < 4; ++i)
#pragma unroll
        for (int j = 0; j < 4; ++j) acc[i][j] += av[i] * wv[j];
    }
    __syncthreads();
  }
#pragma unroll
  for (int i = 0; i < 4; ++i) {
    int row = bm + ty * 4 + i;
    if (row < Nr) {
#pragma unroll
      for (int j = 0; j < 4; ++j) {
        int col = bn + tx * 4 + j;
        C[(size_t)row * M + col] = acc[i][j] + bias[col];
      }
    }
  }
}

// ---------------- edge bias: ebias[e,h] = ea[e,:] @ eW[:,h] + eb[h] ----------------
__global__ __launch_bounds__(256)
void edge_bias_gemm(const float* __restrict__ ea, const float* __restrict__ eW,
                    const float* __restrict__ eb, float* __restrict__ ebias, int E) {
  __shared__ float eas[64 * 33];   // 64 edge rows, padded stride 33 (bank-spread)
  __shared__ float ews[256];       // eW 32x8
  const int tid = threadIdx.x;
  const long e0 = (long)blockIdx.x * 64;
  if (tid < 256) ews[tid] = eW[tid];
  const int nrem = (int)min((long)64, (long)E - e0);
#pragma unroll
  for (int i = 0; i < 8; ++i) {
    int lin = tid + i * 256;       // 2048 contiguous floats
    int r = lin >> 5, c = lin & 31;
    if (r < nrem) eas[r * 33 + c] = ea[e0 * 32 + lin];
  }
  __syncthreads();
  const int el = tid >> 2, h0 = (tid & 3) * 2;
  if (el < nrem) {
    float s0 = eb[h0], s1 = eb[h0 + 1];
#pragma unroll
    for (int i = 0; i < 32; ++i) {
      float a = eas[el * 33 + i];
      s0 += a * ews[i * 8 + h0];
      s1 += a * ews[i * 8 + h0 + 1];
    }
    *(float2*)&ebias[(e0 + el) * 8 + h0] = make_float2(s0, s1);
  }
}

// ---------------- CSR build ----------------
__global__ __launch_bounds__(256)
void edge_hist(const int* __restrict__ ei, int* __restrict__ deg, int E) {
  int e = blockIdx.x * 256 + threadIdx.x;
  if (e < E) atomicAdd(&deg[ei[E + e]], 1);
}

// single block of 1024 threads: exclusive scan of deg (in `pos`) -> offs[0..N], pos=offs copy
__global__ __launch_bounds__(1024)
void scan_offsets(int* __restrict__ pos, int* __restrict__ offs, int N) {
  __shared__ int partial[1024];
  const int t = threadIdx.x;
  const int chunk = (N + 1023) / 1024;
  const int beg = t * chunk;
  const int end = min(beg + chunk, N);
  int sum = 0;
  for (int i = beg; i < end; ++i) sum += pos[i];
  partial[t] = sum;
  __syncthreads();
  for (int off = 1; off < 1024; off <<= 1) {
    int x = (t >= off) ? partial[t - off] : 0;
    __syncthreads();
    partial[t] += x;
    __syncthreads();
  }
  int run = partial[t] - sum;      // exclusive prefix of this thread's chunk
  for (int i = beg; i < end; ++i) {
    int d = pos[i];
    offs[i] = run;
    pos[i] = run;
    run += d;
  }
  if (t == 1023) offs[N] = partial[1023];
}

__global__ __launch_bounds__(256)
void edge_scatter(const int* __restrict__ ei, int* __restrict__ pos,
                  int* __restrict__ csr_src, int* __restrict__ csr_eid, int E) {
  int e = blockIdx.x * 256 + threadIdx.x;
  if (e < E) {
    int d = ei[E + e];
    int p = atomicAdd(&pos[d], 1);
    csr_src[p] = ei[e];
    csr_eid[p] = e;
  }
}

// ---------------- fused per-node attention aggregate ----------------
// one wave per dst node; lane holds floats [lane*2, lane*2+1]; head h = lane>>3
__global__ __launch_bounds__(256)
void node_agg(const int* __restrict__ csr_src, const int* __restrict__ csr_eid,
              const int* __restrict__ offs, const float* __restrict__ q,
              const float* __restrict__ k, const float* __restrict__ v,
              const float* __restrict__ ebias, float* __restrict__ agg, int N) {
  const int wid = threadIdx.x >> 6, lane = threadIdx.x & 63;
  const long n = (long)blockIdx.x * 4 + wid;
  if (n >= N) return;
  const int off = offs[n], end = offs[n + 1];
  const float2 kv = *(const float2*)&k[n * 128 + lane * 2];
  const int h = lane >> 3;
  float acc0 = 0.f, acc1 = 0.f, den = 0.f;
#pragma unroll 2
  for (int i = off; i < end; ++i) {
    const int s = csr_src[i];
    const int eid = csr_eid[i];
    const float2 qv = *(const float2*)&q[(size_t)s * 128 + lane * 2];
    float p = qv.x * kv.x + qv.y * kv.y;
    p += __shfl_xor(p, 1);
    p += __shfl_xor(p, 2);
    p += __shfl_xor(p, 4);
    const float ex = __expf(p * 0.25f + ebias[(size_t)eid * 8 + h]);
    const float2 vv = *(const float2*)&v[(size_t)s * 128 + lane * 2];
    den += ex;
    acc0 += vv.x * ex;
    acc1 += vv.y * ex;
  }
  const float r = 1.f / fmaxf(den, 1e-8f);
  *(float2*)&agg[n * 128 + lane * 2] = make_float2(acc0 * r, acc1 * r);
}

// ---------------- y = LN(x + r) * g + b, rows of 128 (1 wave/row) ----------------
__global__ __launch_bounds__(256)
void add_ln128(const float* __restrict__ x, const float* __restrict__ r,
               const float* __restrict__ g, const float* __restrict__ b,
               float* __restrict__ y, int Nr) {
  const int wid = threadIdx.x >> 6, lane = threadIdx.x & 63;
  const long row = (long)blockIdx.x * 4 + wid;
  if (row >= Nr) return;
  const float2 xv = *(const float2*)&x[row * 128 + lane * 2];
  const float2 rv = *(const float2*)&r[row * 128 + lane * 2];
  float a0 = xv.x + rv.x, a1 = xv.y + rv.y;
  float s = a0 + a1, ss = a0 * a0 + a1 * a1;
#pragma unroll
  for (int off = 32; off; off >>= 1) { s += __shfl_xor(s, off); ss += __shfl_xor(ss, off); }
  const float mu = s * (1.f / 128.f);
  const float inv = rsqrtf(ss * (1.f / 128.f) - mu * mu + LN_EPS);
  const float2 gv = *(const float2*)&g[lane * 2];
  const float2 bv = *(const float2*)&b[lane * 2];
  float2 o;
  o.x = (a0 - mu) * inv * gv.x + bv.x;
  o.y = (a1 - mu) * inv * gv.y + bv.y;
  *(float2*)&y[row * 128 + lane * 2] = o;
}

// ---------------- in-place LN(row of 512) -> exact GELU ----------------
__global__ __launch_bounds__(256)
void ln_gelu512(float* __restrict__ hbuf, const float* __restrict__ g,
                const float* __restrict__ b, int Nr) {
  __shared__ float rs[4], rss[4];
  const long row = blockIdx.x;
  const int tid = threadIdx.x;
  float2 v = *(float2*)&hbuf[row * 512 + tid * 2];
  float s = v.x + v.y, ss = v.x * v.x + v.y * v.y;
#pragma unroll
  for (int off = 32; off; off >>= 1) { s += __shfl_xor(s, off); ss += __shfl_xor(ss, off); }
  const int wid = tid >> 6, lane = tid & 63;
  if (lane == 0) { rs[wid] = s; rss[wid] = ss; }
  __syncthreads();
  s = rs[0] + rs[1] + rs[2] + rs[3];
  ss = rss[0] + rss[1] + rss[2] + rss[3];
  const float mu = s * (1.f / 512.f);
  const float inv = rsqrtf(ss * (1.f / 512.f) - mu * mu + LN_EPS);
  float t0 = (v.x - mu) * inv * g[tid * 2] + b[tid * 2];
  float t1 = (v.y - mu) * inv * g[tid * 2 + 1] + b[tid * 2 + 1];
  v.x = 0.5f * t0 * (1.f + erff(t0 * 0.70710678118654752f));
  v.y = 0.5f * t1 * (1.f + erff(t1 * 0.70710678118654752f));
  *(float2*)&hbuf[row * 512 + tid * 2] = v;
}

extern "C" void kernel_launch(void* const* d_in, const int* in_sizes, int n_in,
                              void* d_out, int out_size, void* d_ws, size_t ws_size,
                              hipStream_t stream) {
  const float* x   = (const float*)d_in[0];
  const int*   ei  = (const int*)d_in[1];
  const float* ea  = (const float*)d_in[2];
  const float* qW  = (const float*)d_in[3];
  const float* qbi = (const float*)d_in[4];
  const float* kW  = (const float*)d_in[5];
  const float* kbi = (const float*)d_in[6];
  const float* vW  = (const float*)d_in[7];
  const float* vbi = (const float*)d_in[8];
  const float* eW  = (const float*)d_in[9];
  const float* eb  = (const float*)d_in[10];
  const float* oW  = (const float*)d_in[11];
  const float* ob  = (const float*)d_in[12];
  const float* ln1_g = (const float*)d_in[13];
  const float* ln1_b = (const float*)d_in[14];
  const float* f1W = (const float*)d_in[15];
  const float* f1b = (const float*)d_in[16];
  const float* lnf_g = (const float*)d_in[17];
  const float* lnf_b = (const float*)d_in[18];
  const float* f2W = (const float*)d_in[19];
  const float* f2b = (const float*)d_in[20];
  const float* ln2_g = (const float*)d_in[21];
  const float* ln2_b = (const float*)d_in[22];
  float* out = (float*)d_out;

  const int N = in_sizes[0] / 128;
  const int E = in_sizes[1] / 2;
  const size_t NH = (size_t)N * 128;   // 6.4M floats

  // workspace layout (floats), lifetime-overlapped; peak = 6*NH (~154 MB):
  //   [0,NH) q -> x1        [NH,2NH) k \
  //   [2NH,3NH) v            [3NH,4NH) ebias -> attnout   } hbuf = [NH,5NH)
  //   [4NH,5NH) agg         /
  //   [5NH,6NH) csr ints (2E+2N+1) -> h2
  float* base = (float*)d_ws;
  float* wq    = base;
  float* wk    = base + NH;
  float* wv    = base + 2 * NH;
  float* ebias = base + 3 * NH;
  float* agg   = base + 4 * NH;
  float* attnout = ebias;
  float* x1    = wq;
  float* hbuf  = wk;
  float* h2    = base + 5 * NH;
  int* ib      = (int*)(base + 5 * NH);
  int* csr_src = ib;
  int* csr_eid = ib + E;
  int* offs    = ib + 2 * (size_t)E;          // N+1
  int* pos     = ib + 2 * (size_t)E + N + 1;  // N (doubles as deg)

  dim3 blk(256);
  dim3 g128((N + 63) / 64, 2);
  dim3 g512((N + 63) / 64, 8);

  // QKV projections
  gemm_bias<<<g128, blk, 0, stream>>>(x, qW, qbi, wq, N, 128, 128);
  gemm_bias<<<g128, blk, 0, stream>>>(x, kW, kbi, wk, N, 128, 128);
  gemm_bias<<<g128, blk, 0, stream>>>(x, vW, vbi, wv, N, 128, 128);

  // edge bias (E x 8)
  edge_bias_gemm<<<dim3((E + 63) / 64), blk, 0, stream>>>(ea, eW, eb, ebias, E);

  // CSR by dst
  hipMemsetAsync(pos, 0, (size_t)N * sizeof(int), stream);
  edge_hist<<<dim3((E + 255) / 256), blk, 0, stream>>>(ei, pos, E);
  scan_offsets<<<dim3(1), dim3(1024), 0, stream>>>(pos, offs, N);
  edge_scatter<<<dim3((E + 255) / 256), blk, 0, stream>>>(ei, pos, csr_src, csr_eid, E);

  // fused scores + softmax + weighted aggregation (one wave per node)
  node_agg<<<dim3((N + 3) / 4), blk, 0, stream>>>(csr_src, csr_eid, offs,
                                                  wq, wk, wv, ebias, agg, N);

  // output projection + residual LN
  gemm_bias<<<g128, blk, 0, stream>>>(agg, oW, ob, attnout, N, 128, 128);
  add_ln128<<<dim3((N + 3) / 4), blk, 0, stream>>>(x, attnout, ln1_g, ln1_b, x1, N);

  // FFN
  gemm_bias<<<g512, blk, 0, stream>>>(x1, f1W, f1b, hbuf, N, 128, 512);
  ln_gelu512<<<dim3(N), blk, 0, stream>>>(hbuf, lnf_g, lnf_b, N);
  gemm_bias<<<g128, blk, 0, stream>>>(hbuf, f2W, f2b, h2, N, 512, 128);
  add_ln128<<<dim3((N + 3) / 4), blk, 0, stream>>>(x1, h2, ln2_g, ln2_b, out, N);
}

// Round 3
// 535.362 us; speedup vs baseline: 2.6879x; 1.5667x over previous
//
#include <hip/hip_runtime.h>
#include <math.h>

#define LN_EPS 1e-5f

typedef __attribute__((ext_vector_type(8))) __bf16 bf16x8;
typedef __attribute__((ext_vector_type(4))) float f32x4;

__device__ inline float bf2f(unsigned short u) {
  union { unsigned int i; float f; } x; x.i = ((unsigned int)u) << 16; return x.f;
}
__device__ inline unsigned short f2bf(float f) {
  union { float f; unsigned int i; } x; x.f = f;
  unsigned int r = (x.i + 0x7FFFu + ((x.i >> 16) & 1u)) >> 16;   // RNE
  return (unsigned short)r;
}
__device__ inline void gload_lds16(const void* g, void* l) {
  __builtin_amdgcn_global_load_lds((const __attribute__((address_space(1))) void*)g,
                                   (__attribute__((address_space(3))) void*)l, 16, 0, 0);
}

// ---------------- f32 -> bf16 elementwise ----------------
__global__ __launch_bounds__(256)
void to_bf16(const float* __restrict__ in, unsigned short* __restrict__ outp, long n) {
  long i = ((long)blockIdx.x * 256 + threadIdx.x) * 4;
  if (i >= n) return;
  float4 v = *(const float4*)&in[i];
  ushort4 o = { f2bf(v.x), f2bf(v.y), f2bf(v.z), f2bf(v.w) };
  *(ushort4*)&outp[i] = o;
}

// ---------------- W[K,M] f32 -> Wt[M,K] bf16 ----------------
__global__ __launch_bounds__(256)
void transpose_w(const float* __restrict__ W, unsigned short* __restrict__ Wt, int K, int M) {
  __shared__ float t[32][33];
  const int k0 = blockIdx.x * 32, m0 = blockIdx.y * 32;
  const int tx = threadIdx.x & 31, ty = threadIdx.x >> 5;  // 32 x 8
#pragma unroll
  for (int i = 0; i < 32; i += 8)
    t[ty + i][tx] = W[(size_t)(k0 + ty + i) * M + m0 + tx];
  __syncthreads();
#pragma unroll
  for (int i = 0; i < 32; i += 8)
    Wt[(size_t)(m0 + ty + i) * K + k0 + tx] = f2bf(t[tx][ty + i]);
}

// ---------------- bf16 MFMA GEMM: C[N,M] = A[N,K] @ Wt[M,K]^T + bias ----------------
// 128x128 tile, BK=64, 4 waves (2x2), 16 frags/wave of 16x16x32.
// LDS linear dest via global_load_lds; XOR swizzle (chunk j ^= row&7) applied on the
// global SOURCE address and again on the ds_read side (same involution).
template<bool OBF>
__global__ __launch_bounds__(256)
void gemm_mfma(const unsigned short* __restrict__ A, const unsigned short* __restrict__ Wt,
               const float* __restrict__ bias, void* __restrict__ Cout,
               int Nr, int K, int M) {
  __shared__ __align__(16) unsigned short As[128 * 64];
  __shared__ __align__(16) unsigned short Bs[128 * 64];
  const int tid = threadIdx.x;
  const int bm = blockIdx.x * 128, bn = blockIdx.y * 128;
  const int lane = tid & 63;
  const int wr = (tid >> 6) >> 1, wc = (tid >> 6) & 1;
  f32x4 acc[4][4] = {};
  const int nkt = K >> 6;
  for (int kt = 0; kt < nkt; ++kt) {
#pragma unroll
    for (int i = 0; i < 4; ++i) {          // 1024 16B-chunks per tile, 256 threads
      int c = tid + i * 256;
      int row = c >> 3;
      int j = (c & 7) ^ (row & 7);         // content chunk for linear slot c&7
      int ar = bm + row; ar = ar < Nr ? ar : Nr - 1;
      gload_lds16(A + (size_t)ar * K + kt * 64 + j * 8, As + (size_t)c * 8);
      gload_lds16(Wt + (size_t)(bn + row) * K + kt * 64 + j * 8, Bs + (size_t)c * 8);
    }
    __syncthreads();
#pragma unroll
    for (int ks = 0; ks < 2; ++ks) {
      bf16x8 af[4], bfr[4];
#pragma unroll
      for (int f = 0; f < 4; ++f) {
        int rowa = wr * 64 + f * 16 + (lane & 15);
        int ja = (ks * 4 + (lane >> 4)) ^ (rowa & 7);
        af[f] = *(const bf16x8*)(As + rowa * 64 + ja * 8);
        int rowb = wc * 64 + f * 16 + (lane & 15);
        int jb = (ks * 4 + (lane >> 4)) ^ (rowb & 7);
        bfr[f] = *(const bf16x8*)(Bs + rowb * 64 + jb * 8);
      }
#pragma unroll
      for (int fr = 0; fr < 4; ++fr)
#pragma unroll
        for (int fc = 0; fc < 4; ++fc)
          acc[fr][fc] = __builtin_amdgcn_mfma_f32_16x16x32_bf16(af[fr], bfr[fc], acc[fr][fc], 0, 0, 0);
    }
    __syncthreads();
  }
#pragma unroll
  for (int fr = 0; fr < 4; ++fr) {
#pragma unroll
    for (int j = 0; j < 4; ++j) {
      int row = bm + wr * 64 + fr * 16 + (lane >> 4) * 4 + j;
      if (row < Nr) {
#pragma unroll
        for (int fc = 0; fc < 4; ++fc) {
          int col = bn + wc * 64 + fc * 16 + (lane & 15);
          float v = acc[fr][fc][j] + bias[col];
          if (OBF) ((unsigned short*)Cout)[(size_t)row * M + col] = f2bf(v);
          else     ((float*)Cout)[(size_t)row * M + col] = v;
        }
      }
    }
  }
}

// ---------------- edge bias: ebias[e,h] = ea[e,:] @ eW[:,h] + eb[h] ----------------
__global__ __launch_bounds__(256)
void edge_bias_gemm(const float* __restrict__ ea, const float* __restrict__ eW,
                    const float* __restrict__ eb, float* __restrict__ ebias, int E) {
  __shared__ float eas[64 * 33];
  __shared__ float ews[256];
  const int tid = threadIdx.x;
  const long e0 = (long)blockIdx.x * 64;
  if (tid < 256) ews[tid] = eW[tid];
  const int nrem = (int)min((long)64, (long)E - e0);
#pragma unroll
  for (int i = 0; i < 8; ++i) {
    int lin = tid + i * 256;
    int r = lin >> 5, c = lin & 31;
    if (r < nrem) eas[r * 33 + c] = ea[e0 * 32 + lin];
  }
  __syncthreads();
  const int el = tid >> 2, h0 = (tid & 3) * 2;
  if (el < nrem) {
    float s0 = eb[h0], s1 = eb[h0 + 1];
#pragma unroll
    for (int i = 0; i < 32; ++i) {
      float a = eas[el * 33 + i];
      s0 += a * ews[i * 8 + h0];
      s1 += a * ews[i * 8 + h0 + 1];
    }
    *(float2*)&ebias[(e0 + el) * 8 + h0] = make_float2(s0, s1);
  }
}

// ---------------- CSR build ----------------
__global__ __launch_bounds__(256)
void edge_hist(const int* __restrict__ ei, int* __restrict__ deg, int E) {
  int e = blockIdx.x * 256 + threadIdx.x;
  if (e < E) atomicAdd(&deg[ei[E + e]], 1);
}

__global__ __launch_bounds__(1024)
void scan_offsets(int* __restrict__ pos, int* __restrict__ offs, int N) {
  __shared__ int partial[1024];
  const int t = threadIdx.x;
  const int chunk = (N + 1023) / 1024;
  const int beg = t * chunk;
  const int end = min(beg + chunk, N);
  int sum = 0;
  for (int i = beg; i < end; ++i) sum += pos[i];
  partial[t] = sum;
  __syncthreads();
  for (int off = 1; off < 1024; off <<= 1) {
    int x = (t >= off) ? partial[t - off] : 0;
    __syncthreads();
    partial[t] += x;
    __syncthreads();
  }
  int run = partial[t] - sum;
  for (int i = beg; i < end; ++i) {
    int d = pos[i];
    offs[i] = run;
    pos[i] = run;
    run += d;
  }
  if (t == 1023) offs[N] = partial[1023];
}

__global__ __launch_bounds__(256)
void edge_scatter(const int* __restrict__ ei, int* __restrict__ pos,
                  int* __restrict__ csr_src, int* __restrict__ csr_eid, int E) {
  int e = blockIdx.x * 256 + threadIdx.x;
  if (e < E) {
    int d = ei[E + e];
    int p = atomicAdd(&pos[d], 1);
    csr_src[p] = ei[e];
    csr_eid[p] = e;
  }
}

// ---------------- fused per-node attention aggregate (bf16 q/k/v) ----------------
__global__ __launch_bounds__(256)
void node_agg(const int* __restrict__ csr_src, const int* __restrict__ csr_eid,
              const int* __restrict__ offs, const unsigned short* __restrict__ q,
              const unsigned short* __restrict__ k, const unsigned short* __restrict__ v,
              const float* __restrict__ ebias, unsigned short* __restrict__ agg, int N) {
  const int wid = threadIdx.x >> 6, lane = threadIdx.x & 63;
  const long n = (long)blockIdx.x * 4 + wid;
  if (n >= N) return;
  const int off = offs[n], end = offs[n + 1];
  const ushort2 kv2 = *(const ushort2*)&k[n * 128 + lane * 2];
  const float k0 = bf2f(kv2.x), k1 = bf2f(kv2.y);
  const int h = lane >> 3;
  float acc0 = 0.f, acc1 = 0.f, den = 0.f;
#pragma unroll 2
  for (int i = off; i < end; ++i) {
    const int s = csr_src[i];
    const int eid = csr_eid[i];
    const ushort2 qv2 = *(const ushort2*)&q[(size_t)s * 128 + lane * 2];
    float p = bf2f(qv2.x) * k0 + bf2f(qv2.y) * k1;
    p += __shfl_xor(p, 1);
    p += __shfl_xor(p, 2);
    p += __shfl_xor(p, 4);
    const float ex = __expf(p * 0.25f + ebias[(size_t)eid * 8 + h]);
    const ushort2 vv2 = *(const ushort2*)&v[(size_t)s * 128 + lane * 2];
    den += ex;
    acc0 += bf2f(vv2.x) * ex;
    acc1 += bf2f(vv2.y) * ex;
  }
  const float r = 1.f / fmaxf(den, 1e-8f);
  ushort2 o; o.x = f2bf(acc0 * r); o.y = f2bf(acc1 * r);
  *(ushort2*)&agg[n * 128 + lane * 2] = o;
}

// ---------------- y = LN(x + r), optional bf16 copy ----------------
template<bool WBF>
__global__ __launch_bounds__(256)
void add_ln128(const float* __restrict__ x, const float* __restrict__ r,
               const float* __restrict__ g, const float* __restrict__ b,
               float* __restrict__ y, unsigned short* __restrict__ ybf, int Nr) {
  const int wid = threadIdx.x >> 6, lane = threadIdx.x & 63;
  const long row = (long)blockIdx.x * 4 + wid;
  if (row >= Nr) return;
  const float2 xv = *(const float2*)&x[row * 128 + lane * 2];
  const float2 rv = *(const float2*)&r[row * 128 + lane * 2];
  float a0 = xv.x + rv.x, a1 = xv.y + rv.y;
  float s = a0 + a1, ss = a0 * a0 + a1 * a1;
#pragma unroll
  for (int off = 32; off; off >>= 1) { s += __shfl_xor(s, off); ss += __shfl_xor(ss, off); }
  const float mu = s * (1.f / 128.f);
  const float inv = rsqrtf(ss * (1.f / 128.f) - mu * mu + LN_EPS);
  const float2 gv = *(const float2*)&g[lane * 2];
  const float2 bv = *(const float2*)&b[lane * 2];
  float2 o;
  o.x = (a0 - mu) * inv * gv.x + bv.x;
  o.y = (a1 - mu) * inv * gv.y + bv.y;
  *(float2*)&y[row * 128 + lane * 2] = o;
  if (WBF) {
    ushort2 ob2; ob2.x = f2bf(o.x); ob2.y = f2bf(o.y);
    *(ushort2*)&ybf[row * 128 + lane * 2] = ob2;
  }
}

// ---------------- in-place LN(row of 512) -> exact GELU, bf16 ----------------
__global__ __launch_bounds__(256)
void ln_gelu512(unsigned short* __restrict__ hbuf, const float* __restrict__ g,
                const float* __restrict__ b, int Nr) {
  __shared__ float rs[4], rss[4];
  const long row = blockIdx.x;
  const int tid = threadIdx.x;
  ushort2 u = *(ushort2*)&hbuf[row * 512 + tid * 2];
  float v0 = bf2f(u.x), v1 = bf2f(u.y);
  float s = v0 + v1, ss = v0 * v0 + v1 * v1;
#pragma unroll
  for (int off = 32; off; off >>= 1) { s += __shfl_xor(s, off); ss += __shfl_xor(ss, off); }
  const int wid = tid >> 6, lane = tid & 63;
  if (lane == 0) { rs[wid] = s; rss[wid] = ss; }
  __syncthreads();
  s = rs[0] + rs[1] + rs[2] + rs[3];
  ss = rss[0] + rss[1] + rss[2] + rss[3];
  const float mu = s * (1.f / 512.f);
  const float inv = rsqrtf(ss * (1.f / 512.f) - mu * mu + LN_EPS);
  float t0 = (v0 - mu) * inv * g[tid * 2] + b[tid * 2];
  float t1 = (v1 - mu) * inv * g[tid * 2 + 1] + b[tid * 2 + 1];
  t0 = 0.5f * t0 * (1.f + erff(t0 * 0.70710678118654752f));
  t1 = 0.5f * t1 * (1.f + erff(t1 * 0.70710678118654752f));
  ushort2 o; o.x = f2bf(t0); o.y = f2bf(t1);
  *(ushort2*)&hbuf[row * 512 + tid * 2] = o;
}

extern "C" void kernel_launch(void* const* d_in, const int* in_sizes, int n_in,
                              void* d_out, int out_size, void* d_ws, size_t ws_size,
                              hipStream_t stream) {
  const float* x   = (const float*)d_in[0];
  const int*   ei  = (const int*)d_in[1];
  const float* ea  = (const float*)d_in[2];
  const float* qW  = (const float*)d_in[3];
  const float* qbi = (const float*)d_in[4];
  const float* kW  = (const float*)d_in[5];
  const float* kbi = (const float*)d_in[6];
  const float* vW  = (const float*)d_in[7];
  const float* vbi = (const float*)d_in[8];
  const float* eW  = (const float*)d_in[9];
  const float* eb  = (const float*)d_in[10];
  const float* oW  = (const float*)d_in[11];
  const float* ob  = (const float*)d_in[12];
  const float* ln1_g = (const float*)d_in[13];
  const float* ln1_b = (const float*)d_in[14];
  const float* f1W = (const float*)d_in[15];
  const float* f1b = (const float*)d_in[16];
  const float* lnf_g = (const float*)d_in[17];
  const float* lnf_b = (const float*)d_in[18];
  const float* f2W = (const float*)d_in[19];
  const float* f2b = (const float*)d_in[20];
  const float* ln2_g = (const float*)d_in[21];
  const float* ln2_b = (const float*)d_in[22];
  float* out = (float*)d_out;

  const int N = in_sizes[0] / 128;
  const int E = in_sizes[1] / 2;
  const size_t NH = (size_t)N * 128;

  // workspace (float units), lifetime-overlapped, peak ~6.02*NH (~154 MB):
  //  [0,.5) x_bf -> x1_bf     [.5,1) q bf16   [1,1.5) k bf16   [1.5,2) v bf16
  //  [2,3)  ebias f32 -> attnout f32          [2,4) hbuf bf16 (后期)
  //  [3,3.5) agg bf16         [3.5,3.77) csr ints
  //  [4,5)  x1 f32            [5,6) h2 f32    [6,6.02) Wt weights bf16
  float* F = (float*)d_ws;
  unsigned short* xbf  = (unsigned short*)(F);
  unsigned short* wq   = (unsigned short*)(F + NH / 2);
  unsigned short* wk   = (unsigned short*)(F + NH);
  unsigned short* wv   = (unsigned short*)(F + NH * 3 / 2);
  float*          ebias = F + 2 * NH;
  unsigned short* hbufb = (unsigned short*)(F + 2 * NH);
  unsigned short* aggb  = (unsigned short*)(F + 3 * NH);
  int* ib      = (int*)(F + NH * 7 / 2);
  int* csr_src = ib;
  int* csr_eid = ib + E;
  int* offs    = ib + 2 * (size_t)E;
  int* pos     = ib + 2 * (size_t)E + N + 1;
  float* attnout = ebias;
  float* x1    = F + 4 * NH;
  unsigned short* x1bf = xbf;
  float* h2    = F + 5 * NH;
  unsigned short* wt = (unsigned short*)(F + 6 * NH);
  unsigned short* qWt  = wt;
  unsigned short* kWt  = wt + 16384;
  unsigned short* vWt  = wt + 32768;
  unsigned short* oWt  = wt + 49152;
  unsigned short* f1Wt = wt + 65536;   // 512x128
  unsigned short* f2Wt = wt + 131072;  // 128x512

  dim3 blk(256);
  dim3 gq((N + 127) / 128, 1);
  dim3 gf1((N + 127) / 128, 4);

  // converts + weight transposes
  to_bf16<<<dim3((int)((NH / 4 + 255) / 256)), blk, 0, stream>>>(x, xbf, (long)NH);
  transpose_w<<<dim3(4, 4), blk, 0, stream>>>(qW, qWt, 128, 128);
  transpose_w<<<dim3(4, 4), blk, 0, stream>>>(kW, kWt, 128, 128);
  transpose_w<<<dim3(4, 4), blk, 0, stream>>>(vW, vWt, 128, 128);
  transpose_w<<<dim3(4, 4), blk, 0, stream>>>(oW, oWt, 128, 128);
  transpose_w<<<dim3(4, 16), blk, 0, stream>>>(f1W, f1Wt, 128, 512);
  transpose_w<<<dim3(16, 4), blk, 0, stream>>>(f2W, f2Wt, 512, 128);

  // QKV projections (bf16 out)
  gemm_mfma<true><<<gq, blk, 0, stream>>>(xbf, qWt, qbi, wq, N, 128, 128);
  gemm_mfma<true><<<gq, blk, 0, stream>>>(xbf, kWt, kbi, wk, N, 128, 128);
  gemm_mfma<true><<<gq, blk, 0, stream>>>(xbf, vWt, vbi, wv, N, 128, 128);

  // edge bias + CSR
  edge_bias_gemm<<<dim3((E + 63) / 64), blk, 0, stream>>>(ea, eW, eb, ebias, E);
  hipMemsetAsync(pos, 0, (size_t)N * sizeof(int), stream);
  edge_hist<<<dim3((E + 255) / 256), blk, 0, stream>>>(ei, pos, E);
  scan_offsets<<<dim3(1), dim3(1024), 0, stream>>>(pos, offs, N);
  edge_scatter<<<dim3((E + 255) / 256), blk, 0, stream>>>(ei, pos, csr_src, csr_eid, E);

  // fused attention aggregate
  node_agg<<<dim3((N + 3) / 4), blk, 0, stream>>>(csr_src, csr_eid, offs,
                                                  wq, wk, wv, ebias, aggb, N);

  // output projection + residual LN (x1 f32 + bf16)
  gemm_mfma<false><<<gq, blk, 0, stream>>>(aggb, oWt, ob, attnout, N, 128, 128);
  add_ln128<true><<<dim3((N + 3) / 4), blk, 0, stream>>>(x, attnout, ln1_g, ln1_b, x1, x1bf, N);

  // FFN
  gemm_mfma<true><<<gf1, blk, 0, stream>>>(x1bf, f1Wt, f1b, hbufb, N, 128, 512);
  ln_gelu512<<<dim3(N), blk, 0, stream>>>(hbufb, lnf_g, lnf_b, N);
  gemm_mfma<false><<<gq, blk, 0, stream>>>(hbufb, f2Wt, f2b, h2, N, 512, 128);
  add_ln128<false><<<dim3((N + 3) / 4), blk, 0, stream>>>(x1, h2, ln2_g, ln2_b, out, nullptr, N);
}

// Round 4
// 407.024 us; speedup vs baseline: 3.5354x; 1.3153x over previous
//
#include <hip/hip_runtime.h>
#include <math.h>

#define LN_EPS 1e-5f

typedef __attribute__((ext_vector_type(8))) __bf16 bf16x8;
typedef __attribute__((ext_vector_type(4))) float f32x4;

__device__ inline float bf2f(unsigned short u) {
  union { unsigned int i; float f; } x; x.i = ((unsigned int)u) << 16; return x.f;
}
__device__ inline unsigned short f2bf(float f) {
  union { float f; unsigned int i; } x; x.f = f;
  unsigned int r = (x.i + 0x7FFFu + ((x.i >> 16) & 1u)) >> 16;   // RNE
  return (unsigned short)r;
}
__device__ inline void gload_lds16(const void* g, void* l) {
  __builtin_amdgcn_global_load_lds((const __attribute__((address_space(1))) void*)g,
                                   (__attribute__((address_space(3))) void*)l, 16, 0, 0);
}

// ---------------- f32 -> bf16 elementwise ----------------
__global__ __launch_bounds__(256)
void to_bf16(const float* __restrict__ in, unsigned short* __restrict__ outp, long n) {
  long i = ((long)blockIdx.x * 256 + threadIdx.x) * 4;
  if (i >= n) return;
  float4 v = *(const float4*)&in[i];
  ushort4 o = { f2bf(v.x), f2bf(v.y), f2bf(v.z), f2bf(v.w) };
  *(ushort4*)&outp[i] = o;
}

// ---------------- W[K,M] f32 -> Wt[M,K] bf16 ----------------
__global__ __launch_bounds__(256)
void transpose_w(const float* __restrict__ W, unsigned short* __restrict__ Wt, int K, int M) {
  __shared__ float t[32][33];
  const int k0 = blockIdx.x * 32, m0 = blockIdx.y * 32;
  const int tx = threadIdx.x & 31, ty = threadIdx.x >> 5;  // 32 x 8
#pragma unroll
  for (int i = 0; i < 32; i += 8)
    t[ty + i][tx] = W[(size_t)(k0 + ty + i) * M + m0 + tx];
  __syncthreads();
#pragma unroll
  for (int i = 0; i < 32; i += 8)
    Wt[(size_t)(m0 + ty + i) * K + k0 + tx] = f2bf(t[tx][ty + i]);
}

// ---------------- bf16 MFMA GEMM: C[N,M] = A[N,K] @ Wt[M,K]^T + bias ----------------
template<bool OBF>
__global__ __launch_bounds__(256)
void gemm_mfma(const unsigned short* __restrict__ A, const unsigned short* __restrict__ Wt,
               const float* __restrict__ bias, void* __restrict__ Cout,
               int Nr, int K, int M) {
  __shared__ __align__(16) unsigned short As[128 * 64];
  __shared__ __align__(16) unsigned short Bs[128 * 64];
  const int tid = threadIdx.x;
  const int bm = blockIdx.x * 128, bn = blockIdx.y * 128;
  const int lane = tid & 63;
  const int wr = (tid >> 6) >> 1, wc = (tid >> 6) & 1;
  f32x4 acc[4][4] = {};
  const int nkt = K >> 6;
  for (int kt = 0; kt < nkt; ++kt) {
#pragma unroll
    for (int i = 0; i < 4; ++i) {
      int c = tid + i * 256;
      int row = c >> 3;
      int j = (c & 7) ^ (row & 7);
      int ar = bm + row; ar = ar < Nr ? ar : Nr - 1;
      gload_lds16(A + (size_t)ar * K + kt * 64 + j * 8, As + (size_t)c * 8);
      gload_lds16(Wt + (size_t)(bn + row) * K + kt * 64 + j * 8, Bs + (size_t)c * 8);
    }
    __syncthreads();
#pragma unroll
    for (int ks = 0; ks < 2; ++ks) {
      bf16x8 af[4], bfr[4];
#pragma unroll
      for (int f = 0; f < 4; ++f) {
        int rowa = wr * 64 + f * 16 + (lane & 15);
        int ja = (ks * 4 + (lane >> 4)) ^ (rowa & 7);
        af[f] = *(const bf16x8*)(As + rowa * 64 + ja * 8);
        int rowb = wc * 64 + f * 16 + (lane & 15);
        int jb = (ks * 4 + (lane >> 4)) ^ (rowb & 7);
        bfr[f] = *(const bf16x8*)(Bs + rowb * 64 + jb * 8);
      }
#pragma unroll
      for (int fr = 0; fr < 4; ++fr)
#pragma unroll
        for (int fc = 0; fc < 4; ++fc)
          acc[fr][fc] = __builtin_amdgcn_mfma_f32_16x16x32_bf16(af[fr], bfr[fc], acc[fr][fc], 0, 0, 0);
    }
    __syncthreads();
  }
#pragma unroll
  for (int fr = 0; fr < 4; ++fr) {
#pragma unroll
    for (int j = 0; j < 4; ++j) {
      int row = bm + wr * 64 + fr * 16 + (lane >> 4) * 4 + j;
      if (row < Nr) {
#pragma unroll
        for (int fc = 0; fc < 4; ++fc) {
          int col = bn + wc * 64 + fc * 16 + (lane & 15);
          float v = acc[fr][fc][j] + bias[col];
          if (OBF) ((unsigned short*)Cout)[(size_t)row * M + col] = f2bf(v);
          else     ((float*)Cout)[(size_t)row * M + col] = v;
        }
      }
    }
  }
}

// ---------------- edge bias: ebias[e,h] = ea[e,:] @ eW[:,h] + eb[h] ----------------
__global__ __launch_bounds__(256)
void edge_bias_gemm(const float* __restrict__ ea, const float* __restrict__ eW,
                    const float* __restrict__ eb, float* __restrict__ ebias, int E) {
  __shared__ float eas[64 * 33];
  __shared__ float ews[256];
  const int tid = threadIdx.x;
  const long e0 = (long)blockIdx.x * 64;
  if (tid < 256) ews[tid] = eW[tid];
  const int nrem = (int)min((long)64, (long)E - e0);
#pragma unroll
  for (int i = 0; i < 8; ++i) {
    int lin = tid + i * 256;
    int r = lin >> 5, c = lin & 31;
    if (r < nrem) eas[r * 33 + c] = ea[e0 * 32 + lin];
  }
  __syncthreads();
  const int el = tid >> 2, h0 = (tid & 3) * 2;
  if (el < nrem) {
    float s0 = eb[h0], s1 = eb[h0 + 1];
#pragma unroll
    for (int i = 0; i < 32; ++i) {
      float a = eas[el * 33 + i];
      s0 += a * ews[i * 8 + h0];
      s1 += a * ews[i * 8 + h0 + 1];
    }
    *(float2*)&ebias[(e0 + el) * 8 + h0] = make_float2(s0, s1);
  }
}

// ---------------- CSR build ----------------
__global__ __launch_bounds__(256)
void edge_hist(const int* __restrict__ ei, int* __restrict__ deg, int E) {
  int e = blockIdx.x * 256 + threadIdx.x;
  if (e < E) atomicAdd(&deg[ei[E + e]], 1);
}

// phase A: per-block (2048 elems) sums of deg
__global__ __launch_bounds__(256)
void deg_block_sum(const int* __restrict__ deg, int* __restrict__ bsum, int N) {
  const int t = threadIdx.x;
  const int beg = blockIdx.x * 2048 + t * 8;
  int s = 0;
#pragma unroll
  for (int j = 0; j < 8; ++j) { int i = beg + j; if (i < N) s += deg[i]; }
#pragma unroll
  for (int off = 32; off; off >>= 1) s += __shfl_xor(s, off);
  __shared__ int ws[4];
  if ((t & 63) == 0) ws[t >> 6] = s;
  __syncthreads();
  if (t == 0) bsum[blockIdx.x] = ws[0] + ws[1] + ws[2] + ws[3];
}

// phase B: exclusive scan of bsum (nb <= 64), one wave; also writes offs[N]=total
__global__ __launch_bounds__(64)
void scan_bsum(int* __restrict__ bsum, int* __restrict__ offs_last, int nb) {
  const int t = threadIdx.x;
  int v = (t < nb) ? bsum[t] : 0;
  int inc = v;
#pragma unroll
  for (int off = 1; off < 64; off <<= 1) {
    int x = __shfl_up(inc, off);
    if (t >= off) inc += x;
  }
  if (t < nb) bsum[t] = inc - v;
  if (t == 63) *offs_last = inc;
}

// phase C: per-block rescan, write offs & pos
__global__ __launch_bounds__(256)
void deg_scan_write(const int* __restrict__ deg, const int* __restrict__ bsum,
                    int* __restrict__ offs, int* __restrict__ pos, int N) {
  const int t = threadIdx.x;
  const int beg = blockIdx.x * 2048 + t * 8;
  int loc[8]; int T = 0;
#pragma unroll
  for (int j = 0; j < 8; ++j) { int i = beg + j; loc[j] = (i < N) ? deg[i] : 0; T += loc[j]; }
  int inc = T;
#pragma unroll
  for (int off = 1; off < 64; off <<= 1) {
    int x = __shfl_up(inc, off);
    if ((t & 63) >= off) inc += x;
  }
  __shared__ int ws[4];
  if ((t & 63) == 63) ws[t >> 6] = inc;   // wave total
  __syncthreads();
  const int wid = t >> 6;
  int wbase = 0;
  for (int w = 0; w < wid; ++w) wbase += ws[w];
  int base = bsum[blockIdx.x] + wbase + inc - T;
#pragma unroll
  for (int j = 0; j < 8; ++j) {
    int i = beg + j;
    if (i < N) { offs[i] = base; pos[i] = base; base += loc[j]; }
  }
}

// scatter: CSR src list + ebias permuted into CSR order (csr_eid eliminated)
__global__ __launch_bounds__(256)
void edge_scatter(const int* __restrict__ ei, int* __restrict__ pos,
                  const float* __restrict__ ebias, int* __restrict__ csr_src,
                  float* __restrict__ ebp, int E) {
  int e = blockIdx.x * 256 + threadIdx.x;
  if (e < E) {
    int d = ei[E + e];
    int p = atomicAdd(&pos[d], 1);
    csr_src[p] = ei[e];
    float4 b0 = *(const float4*)&ebias[(size_t)e * 8];
    float4 b1 = *(const float4*)&ebias[(size_t)e * 8 + 4];
    *(float4*)&ebp[(size_t)p * 8] = b0;
    *(float4*)&ebp[(size_t)p * 8 + 4] = b1;
  }
}

// ---------------- fused per-node attention aggregate (bf16 q/k/v, CSR-ordered ebias) ----------------
__global__ __launch_bounds__(256)
void node_agg(const int* __restrict__ csr_src, const int* __restrict__ offs,
              const unsigned short* __restrict__ q, const unsigned short* __restrict__ k,
              const unsigned short* __restrict__ v, const float* __restrict__ ebp,
              unsigned short* __restrict__ agg, int N) {
  const int wid = threadIdx.x >> 6, lane = threadIdx.x & 63;
  const long n = (long)blockIdx.x * 4 + wid;
  if (n >= N) return;
  const int off = offs[n], end = offs[n + 1];
  const ushort2 kv2 = *(const ushort2*)&k[n * 128 + lane * 2];
  const float k0 = bf2f(kv2.x), k1 = bf2f(kv2.y);
  const int h = lane >> 3;
  float acc0 = 0.f, acc1 = 0.f, den = 0.f;
  int i = off;
  for (; i + 2 <= end; i += 2) {     // 2-wide: 4 independent gathers in flight
    const int s0 = csr_src[i], s1 = csr_src[i + 1];
    const ushort2 qa = *(const ushort2*)&q[(size_t)s0 * 128 + lane * 2];
    const ushort2 va = *(const ushort2*)&v[(size_t)s0 * 128 + lane * 2];
    const ushort2 qb = *(const ushort2*)&q[(size_t)s1 * 128 + lane * 2];
    const ushort2 vb = *(const ushort2*)&v[(size_t)s1 * 128 + lane * 2];
    const float e0 = ebp[(size_t)i * 8 + h];
    const float e1 = ebp[(size_t)(i + 1) * 8 + h];
    float p0 = bf2f(qa.x) * k0 + bf2f(qa.y) * k1;
    float p1 = bf2f(qb.x) * k0 + bf2f(qb.y) * k1;
    p0 += __shfl_xor(p0, 1); p1 += __shfl_xor(p1, 1);
    p0 += __shfl_xor(p0, 2); p1 += __shfl_xor(p1, 2);
    p0 += __shfl_xor(p0, 4); p1 += __shfl_xor(p1, 4);
    const float x0 = __expf(p0 * 0.25f + e0);
    const float x1 = __expf(p1 * 0.25f + e1);
    den += x0 + x1;
    acc0 += bf2f(va.x) * x0 + bf2f(vb.x) * x1;
    acc1 += bf2f(va.y) * x0 + bf2f(vb.y) * x1;
  }
  if (i < end) {
    const int s = csr_src[i];
    const ushort2 qa = *(const ushort2*)&q[(size_t)s * 128 + lane * 2];
    const ushort2 va = *(const ushort2*)&v[(size_t)s * 128 + lane * 2];
    float p = bf2f(qa.x) * k0 + bf2f(qa.y) * k1;
    p += __shfl_xor(p, 1);
    p += __shfl_xor(p, 2);
    p += __shfl_xor(p, 4);
    const float ex = __expf(p * 0.25f + ebp[(size_t)i * 8 + h]);
    den += ex;
    acc0 += bf2f(va.x) * ex;
    acc1 += bf2f(va.y) * ex;
  }
  const float r = 1.f / fmaxf(den, 1e-8f);
  ushort2 o; o.x = f2bf(acc0 * r); o.y = f2bf(acc1 * r);
  *(ushort2*)&agg[n * 128 + lane * 2] = o;
}

// ---------------- y = LN(x + r), optional bf16 copy ----------------
template<bool WBF>
__global__ __launch_bounds__(256)
void add_ln128(const float* __restrict__ x, const float* __restrict__ r,
               const float* __restrict__ g, const float* __restrict__ b,
               float* __restrict__ y, unsigned short* __restrict__ ybf, int Nr) {
  const int wid = threadIdx.x >> 6, lane = threadIdx.x & 63;
  const long row = (long)blockIdx.x * 4 + wid;
  if (row >= Nr) return;
  const float2 xv = *(const float2*)&x[row * 128 + lane * 2];
  const float2 rv = *(const float2*)&r[row * 128 + lane * 2];
  float a0 = xv.x + rv.x, a1 = xv.y + rv.y;
  float s = a0 + a1, ss = a0 * a0 + a1 * a1;
#pragma unroll
  for (int off = 32; off; off >>= 1) { s += __shfl_xor(s, off); ss += __shfl_xor(ss, off); }
  const float mu = s * (1.f / 128.f);
  const float inv = rsqrtf(ss * (1.f / 128.f) - mu * mu + LN_EPS);
  const float2 gv = *(const float2*)&g[lane * 2];
  const float2 bv = *(const float2*)&b[lane * 2];
  float2 o;
  o.x = (a0 - mu) * inv * gv.x + bv.x;
  o.y = (a1 - mu) * inv * gv.y + bv.y;
  *(float2*)&y[row * 128 + lane * 2] = o;
  if (WBF) {
    ushort2 ob2; ob2.x = f2bf(o.x); ob2.y = f2bf(o.y);
    *(ushort2*)&ybf[row * 128 + lane * 2] = ob2;
  }
}

// ---------------- in-place LN(row of 512) -> exact GELU, bf16 ----------------
__global__ __launch_bounds__(256)
void ln_gelu512(unsigned short* __restrict__ hbuf, const float* __restrict__ g,
                const float* __restrict__ b, int Nr) {
  __shared__ float rs[4], rss[4];
  const long row = blockIdx.x;
  const int tid = threadIdx.x;
  ushort2 u = *(ushort2*)&hbuf[row * 512 + tid * 2];
  float v0 = bf2f(u.x), v1 = bf2f(u.y);
  float s = v0 + v1, ss = v0 * v0 + v1 * v1;
#pragma unroll
  for (int off = 32; off; off >>= 1) { s += __shfl_xor(s, off); ss += __shfl_xor(ss, off); }
  const int wid = tid >> 6, lane = tid & 63;
  if (lane == 0) { rs[wid] = s; rss[wid] = ss; }
  __syncthreads();
  s = rs[0] + rs[1] + rs[2] + rs[3];
  ss = rss[0] + rss[1] + rss[2] + rss[3];
  const float mu = s * (1.f / 512.f);
  const float inv = rsqrtf(ss * (1.f / 512.f) - mu * mu + LN_EPS);
  float t0 = (v0 - mu) * inv * g[tid * 2] + b[tid * 2];
  float t1 = (v1 - mu) * inv * g[tid * 2 + 1] + b[tid * 2 + 1];
  t0 = 0.5f * t0 * (1.f + erff(t0 * 0.70710678118654752f));
  t1 = 0.5f * t1 * (1.f + erff(t1 * 0.70710678118654752f));
  ushort2 o; o.x = f2bf(t0); o.y = f2bf(t1);
  *(ushort2*)&hbuf[row * 512 + tid * 2] = o;
}

extern "C" void kernel_launch(void* const* d_in, const int* in_sizes, int n_in,
                              void* d_out, int out_size, void* d_ws, size_t ws_size,
                              hipStream_t stream) {
  const float* x   = (const float*)d_in[0];
  const int*   ei  = (const int*)d_in[1];
  const float* ea  = (const float*)d_in[2];
  const float* qW  = (const float*)d_in[3];
  const float* qbi = (const float*)d_in[4];
  const float* kW  = (const float*)d_in[5];
  const float* kbi = (const float*)d_in[6];
  const float* vW  = (const float*)d_in[7];
  const float* vbi = (const float*)d_in[8];
  const float* eW  = (const float*)d_in[9];
  const float* eb  = (const float*)d_in[10];
  const float* oW  = (const float*)d_in[11];
  const float* ob  = (const float*)d_in[12];
  const float* ln1_g = (const float*)d_in[13];
  const float* ln1_b = (const float*)d_in[14];
  const float* f1W = (const float*)d_in[15];
  const float* f1b = (const float*)d_in[16];
  const float* lnf_g = (const float*)d_in[17];
  const float* lnf_b = (const float*)d_in[18];
  const float* f2W = (const float*)d_in[19];
  const float* f2b = (const float*)d_in[20];
  const float* ln2_g = (const float*)d_in[21];
  const float* ln2_b = (const float*)d_in[22];
  float* out = (float*)d_out;

  const int N = in_sizes[0] / 128;
  const int E = in_sizes[1] / 2;
  const size_t NH = (size_t)N * 128;

  // workspace (float units), lifetime-overlapped, peak ~6.02*NH (~154 MB):
  //  [0,.5) x_bf -> x1_bf   [.5,1) q   [1,1.5) k   [1.5,2) v        (bf16)
  //  [2,3)  ebias f32 -> attnout f32 ;  [2,4) hbuf bf16 (FFN phase)
  //  [3,4)  ebp f32 (CSR-ordered)
  //  [4,4.5) agg bf16 ; [4,5) h2 f32 (FFN phase)
  //  [4.5,~4.65) csr ints (csr_src E, offs N+1, pos N, bsum)
  //  [5,6)  x1 f32 ;  [6,6.02) Wt weights bf16
  float* F = (float*)d_ws;
  unsigned short* xbf  = (unsigned short*)(F);
  unsigned short* wq   = (unsigned short*)(F + NH / 2);
  unsigned short* wk   = (unsigned short*)(F + NH);
  unsigned short* wv   = (unsigned short*)(F + NH * 3 / 2);
  float*          ebias = F + 2 * NH;
  unsigned short* hbufb = (unsigned short*)(F + 2 * NH);
  float*          ebp   = F + 3 * NH;
  unsigned short* aggb  = (unsigned short*)(F + 4 * NH);
  float*          h2    = F + 4 * NH;
  int* ib      = (int*)(F + 4 * NH + NH / 2);
  int* csr_src = ib;
  int* offs    = ib + E;
  int* pos     = ib + E + N + 1;
  int* bsum    = ib + E + 2 * N + 1;
  float* attnout = ebias;
  float* x1    = F + 5 * NH;
  unsigned short* x1bf = xbf;
  unsigned short* wt = (unsigned short*)(F + 6 * NH);
  unsigned short* qWt  = wt;
  unsigned short* kWt  = wt + 16384;
  unsigned short* vWt  = wt + 32768;
  unsigned short* oWt  = wt + 49152;
  unsigned short* f1Wt = wt + 65536;   // 512x128
  unsigned short* f2Wt = wt + 131072;  // 128x512

  dim3 blk(256);
  dim3 gq((N + 127) / 128, 1);
  dim3 gf1((N + 127) / 128, 4);
  const int nb = (N + 2047) / 2048;    // blocks for the deg scan (<= 64)

  // converts + weight transposes
  to_bf16<<<dim3((int)((NH / 4 + 255) / 256)), blk, 0, stream>>>(x, xbf, (long)NH);
  transpose_w<<<dim3(4, 4), blk, 0, stream>>>(qW, qWt, 128, 128);
  transpose_w<<<dim3(4, 4), blk, 0, stream>>>(kW, kWt, 128, 128);
  transpose_w<<<dim3(4, 4), blk, 0, stream>>>(vW, vWt, 128, 128);
  transpose_w<<<dim3(4, 4), blk, 0, stream>>>(oW, oWt, 128, 128);
  transpose_w<<<dim3(4, 16), blk, 0, stream>>>(f1W, f1Wt, 128, 512);
  transpose_w<<<dim3(16, 4), blk, 0, stream>>>(f2W, f2Wt, 512, 128);

  // QKV projections (bf16 out)
  gemm_mfma<true><<<gq, blk, 0, stream>>>(xbf, qWt, qbi, wq, N, 128, 128);
  gemm_mfma<true><<<gq, blk, 0, stream>>>(xbf, kWt, kbi, wk, N, 128, 128);
  gemm_mfma<true><<<gq, blk, 0, stream>>>(xbf, vWt, vbi, wv, N, 128, 128);

  // edge bias + CSR (multi-block scan)
  edge_bias_gemm<<<dim3((E + 63) / 64), blk, 0, stream>>>(ea, eW, eb, ebias, E);
  hipMemsetAsync(pos, 0, (size_t)N * sizeof(int), stream);
  edge_hist<<<dim3((E + 255) / 256), blk, 0, stream>>>(ei, pos, E);
  deg_block_sum<<<dim3(nb), blk, 0, stream>>>(pos, bsum, N);
  scan_bsum<<<dim3(1), dim3(64), 0, stream>>>(bsum, offs + N, nb);
  deg_scan_write<<<dim3(nb), blk, 0, stream>>>(pos, bsum, offs, pos, N);
  edge_scatter<<<dim3((E + 255) / 256), blk, 0, stream>>>(ei, pos, ebias, csr_src, ebp, E);

  // fused attention aggregate
  node_agg<<<dim3((N + 3) / 4), blk, 0, stream>>>(csr_src, offs, wq, wk, wv, ebp, aggb, N);

  // output projection + residual LN (x1 f32 + bf16)
  gemm_mfma<false><<<gq, blk, 0, stream>>>(aggb, oWt, ob, attnout, N, 128, 128);
  add_ln128<true><<<dim3((N + 3) / 4), blk, 0, stream>>>(x, attnout, ln1_g, ln1_b, x1, x1bf, N);

  // FFN
  gemm_mfma<true><<<gf1, blk, 0, stream>>>(x1bf, f1Wt, f1b, hbufb, N, 128, 512);
  ln_gelu512<<<dim3(N), blk, 0, stream>>>(hbufb, lnf_g, lnf_b, N);
  gemm_mfma<false><<<gq, blk, 0, stream>>>(hbufb, f2Wt, f2b, h2, N, 512, 128);
  add_ln128<false><<<dim3((N + 3) / 4), blk, 0, stream>>>(x1, h2, ln2_g, ln2_b, out, nullptr, N);
}